// Round 8
// baseline (307.336 us; speedup 1.0000x reference)
//
#include <hip/hip_runtime.h>
#include <cstdint>
#include <cstddef>

typedef unsigned short u16;
typedef __attribute__((ext_vector_type(4))) float f32x4;
typedef __attribute__((ext_vector_type(8))) short bf16x8;

__device__ __forceinline__ u16 f2bf(float f) {
  unsigned int u = __builtin_bit_cast(unsigned int, f);
  u += 0x7fffu + ((u >> 16) & 1u);
  return (u16)(u >> 16);
}

// async global->LDS DMA, 16B per lane. LDS dest = uniform base + lane*16.
__device__ __forceinline__ void gl_lds16(const u16* g, u16* lds_base) {
  __builtin_amdgcn_global_load_lds(
      (const __attribute__((address_space(1))) unsigned int*)g,
      (__attribute__((address_space(3))) unsigned int*)lds_base, 16, 0, 0);
}

// ---------------- weight transpose + fp32->bf16 ----------------
__global__ __launch_bounds__(256) void transpose_w(const float* __restrict__ src,
                                                   u16* __restrict__ dst,
                                                   int K, int N) {
  __shared__ float tile[32][33];
  int n0 = blockIdx.x * 32, k0 = blockIdx.y * 32;
  int tx = threadIdx.x & 31, ty = threadIdx.x >> 5;  // 32 x 8
#pragma unroll
  for (int i = 0; i < 4; ++i)
    tile[ty + i * 8][tx] = src[(size_t)(k0 + ty + i * 8) * N + n0 + tx];
  __syncthreads();
#pragma unroll
  for (int i = 0; i < 4; ++i)
    dst[(size_t)(n0 + ty + i * 8) * K + k0 + tx] = f2bf(tile[tx][ty + i * 8]);
}

// ---------------- V transpose: qkvb [B*T][2304] -> vt [24][64][2048] ----------------
__global__ __launch_bounds__(256) void transpose_v(const u16* __restrict__ qkvb,
                                                   u16* __restrict__ vt) {
  __shared__ u16 tile[64 * 72];
  int t0 = blockIdx.x * 64;
  int bh = blockIdx.y;
  int b = bh / 12, h = bh % 12;
  int tid = threadIdx.x;
  int c8 = tid & 7, r = tid >> 3;
#pragma unroll
  for (int i = 0; i < 2; ++i) {
    int rr = r + i * 32;
    *(uint4*)&tile[rr * 72 + c8 * 8] =
        *(const uint4*)&qkvb[(size_t)(b * 2048 + t0 + rr) * 2304 + 1536 + h * 64 + c8 * 8];
  }
  __syncthreads();
#pragma unroll
  for (int i = 0; i < 2; ++i) {
    int dr = r + i * 32;
    u16 tmp[8];
#pragma unroll
    for (int j = 0; j < 8; ++j) tmp[j] = tile[(c8 * 8 + j) * 72 + dr];
    *(uint4*)&vt[((size_t)bh * 64 + dr) * 2048 + t0 + c8 * 8] = *(uint4*)tmp;
  }
}

__global__ void zero_counter(unsigned int* c) {
  if (threadIdx.x == 0) *c = 0u;
}

// ---------------- float4 copy (seed residual for split-K atomics) ----------------
__global__ __launch_bounds__(256) void copy_f32(const float* __restrict__ src,
                                                float* __restrict__ dst, int n4) {
  int i = blockIdx.x * 256 + threadIdx.x;
  if (i < n4) *(float4*)(dst + i * 4) = *(const float4*)(src + i * 4);
}

// ---------------- LayerNorm (row = 768 fp32) -> bf16, float4 loads ----------------
__global__ __launch_bounds__(192) void ln_rows(const float* __restrict__ x,
                                               const float* __restrict__ g,
                                               const float* __restrict__ bb,
                                               u16* __restrict__ out) {
  int row = blockIdx.x;
  int t = threadIdx.x;  // 0..191, one float4 each
  float4 v = *(const float4*)(x + (size_t)row * 768 + t * 4);
  float s = v.x + v.y + v.z + v.w;
  float sq = v.x * v.x + v.y * v.y + v.z * v.z + v.w * v.w;
#pragma unroll
  for (int o = 32; o > 0; o >>= 1) {
    s += __shfl_down(s, o);
    sq += __shfl_down(sq, o);
  }
  __shared__ float ss[3], s2[3];
  int w = t >> 6;
  if ((t & 63) == 0) { ss[w] = s; s2[w] = sq; }
  __syncthreads();
  s = ss[0] + ss[1] + ss[2];
  sq = s2[0] + s2[1] + s2[2];
  float mu = s * (1.f / 768.f);
  float var = sq * (1.f / 768.f) - mu * mu;
  float rs = rsqrtf(var + 1e-5f);
  float4 gv = *(const float4*)(g + t * 4);
  float4 bv = *(const float4*)(bb + t * 4);
  u16 o4[4];
  o4[0] = f2bf((v.x - mu) * rs * gv.x + bv.x);
  o4[1] = f2bf((v.y - mu) * rs * gv.y + bv.y);
  o4[2] = f2bf((v.z - mu) * rs * gv.z + bv.z);
  o4[3] = f2bf((v.w - mu) * rs * gv.w + bv.w);
  *(uint2*)(out + (size_t)row * 768 + t * 4) = *(uint2*)o4;
}

// ---------------- bf16 MFMA GEMM: C = A[M,K] @ BT[N,K]^T ----------------
// DMA staging + XOR-swizzled LDS; TN 128 (2x2 waves) or 64 (4x1 waves).
// SPLITK: blockIdx.z selects K-half (EPI must be 3 = fp32 atomicAdd partials;
// destination pre-seeded with the residual by copy_f32).
// EPI: 0 = store bf16; 2 = exact GELU -> bf16; 3 = atomicAdd fp32
template <int EPI, int TN, int SPLITK>
__global__ __launch_bounds__(256, 3) void gemm_bt(const u16* __restrict__ A,
                                                  const u16* __restrict__ BT,
                                                  int M, int N, int K,
                                                  float* __restrict__ outF,
                                                  u16* __restrict__ outB) {
  constexpr int MT = (TN == 128) ? 4 : 2;  // m-frags per wave
  __shared__ __align__(16) u16 Al[128 * 64];
  __shared__ __align__(16) u16 Bl[TN * 64];
  int tid = threadIdx.x;
  int lane = tid & 63, w = tid >> 6;
  int l16 = lane & 15, quad = lane >> 4;
  int swz = l16 & 7;
  int wm = (TN == 128) ? (w >> 1) : w;
  int wn = (TN == 128) ? (w & 1) : 0;
  size_t rowA0 = (size_t)blockIdx.y * 128;
  size_t rowB0 = (size_t)blockIdx.x * TN;
  int kbeg = (SPLITK == 2) ? (int)blockIdx.z * (K >> 1) : 0;
  int kend = (SPLITK == 2) ? kbeg + (K >> 1) : K;

  f32x4 acc[MT][4] = {};

  for (int k0 = kbeg; k0 < kend; k0 += 64) {
    __syncthreads();
#pragma unroll
    for (int i = 0; i < 4; ++i) {
      int cbase = (i * 4 + w) * 64;
      int chunk = cbase + lane;
      int r = chunk >> 3, c8 = (chunk & 7) ^ (r & 7);  // swizzled source chunk
      gl_lds16(&A[(rowA0 + r) * (size_t)K + k0 + c8 * 8], &Al[cbase * 8]);
    }
#pragma unroll
    for (int i = 0; i < TN / 32; ++i) {
      int cbase = (i * 4 + w) * 64;
      int chunk = cbase + lane;
      int r = chunk >> 3, c8 = (chunk & 7) ^ (r & 7);
      gl_lds16(&BT[(rowB0 + r) * (size_t)K + k0 + c8 * 8], &Bl[cbase * 8]);
    }
    __syncthreads();
#pragma unroll
    for (int ks = 0; ks < 2; ++ks) {
      int c = ks * 4 + quad;
      bf16x8 af[MT], bf[4];
#pragma unroll
      for (int mt = 0; mt < MT; ++mt)
        af[mt] = *(const bf16x8*)&Al[(wm * (MT * 16) + mt * 16 + l16) * 64 + (c ^ swz) * 8];
#pragma unroll
      for (int nt = 0; nt < 4; ++nt)
        bf[nt] = *(const bf16x8*)&Bl[(wn * 64 + nt * 16 + l16) * 64 + (c ^ swz) * 8];
#pragma unroll
      for (int mt = 0; mt < MT; ++mt)
#pragma unroll
        for (int nt = 0; nt < 4; ++nt)
          acc[mt][nt] = __builtin_amdgcn_mfma_f32_16x16x32_bf16(af[mt], bf[nt], acc[mt][nt], 0, 0, 0);
    }
  }

#pragma unroll
  for (int mt = 0; mt < MT; ++mt) {
#pragma unroll
    for (int i = 0; i < 4; ++i) {
      size_t row = rowA0 + wm * (MT * 16) + mt * 16 + quad * 4 + i;
#pragma unroll
      for (int nt = 0; nt < 4; ++nt) {
        size_t col = rowB0 + wn * 64 + nt * 16 + l16;
        float v = acc[mt][nt][i];
        if (EPI == 0) {
          outB[row * N + col] = f2bf(v);
        } else if (EPI == 3) {
          atomicAdd(&outF[row * N + col], v);
        } else {
          float ge = 0.5f * v * (1.f + erff(v * 0.70710678118654752f));
          outB[row * N + col] = f2bf(ge);
        }
      }
    }
  }
}

// ---------------- causal flash attention (LDS-staged, swizzled, KB=128) ----
// qkv: [B*T, 2304] bf16 (q|k|v); vt: [24][64][2048] bf16; y: [B*T, 768] bf16
// Fixed-max softmax, per-lane l partials, diagonal k-block peeled (mask-free main loop).
__global__ __launch_bounds__(256, 3) void flash_attn(const u16* __restrict__ qkv,
                                                     const u16* __restrict__ vt,
                                                     u16* __restrict__ y,
                                                     unsigned int* __restrict__ ctr) {
  __shared__ __align__(16) u16 Kl[128 * 64];   // [tok][d], chunk-swizzled
  __shared__ __align__(16) u16 Vl[64 * 128];   // [d][tok], chunk-swizzled
  __shared__ __align__(16) u16 Pl[4][16 * 136];
  __shared__ unsigned int s_unit;

  int tid = threadIdx.x;
  int lane = tid & 63, w = tid >> 6;
  int l16 = lane & 15, quad = lane >> 4;
  int swz = l16 & 7;
  u16* Pw = &Pl[w][0];

  for (;;) {
    __syncthreads();
    if (tid == 0) s_unit = atomicAdd(ctr, 1u);
    __syncthreads();
    unsigned int u = s_unit;
    if (u >= 768u) return;

    int qt = 31 - (int)(u / 24u);  // heavy q-tiles first
    int bh = (int)(u % 24u);
    int b = bh / 12, h = bh % 12;
    int qw = qt * 64 + w * 16;

    const u16* base = qkv + (size_t)b * 2048 * 2304;
    const u16* vbase = vt + (size_t)bh * 64 * 2048;

    bf16x8 qf0, qf1;
    {
      const u16* qp = base + (size_t)(qw + l16) * 2304 + h * 64 + quad * 8;
      qf0 = *(const bf16x8*)qp;
      qf1 = *(const bf16x8*)(qp + 32);
    }

    f32x4 O[4] = {};
    float l_i[4] = {0.f, 0.f, 0.f, 0.f};  // per-lane partial row sums

    int nkb = qt / 2 + 1;
    const float sc = 0.125f * 1.44269504088896340736f;
    for (int kb = 0; kb < nkb; ++kb) {
      int kt0 = kb << 7;
      __syncthreads();
      // stage K [128 tok][64 d] via DMA, swizzled
#pragma unroll
      for (int i = 0; i < 4; ++i) {
        int cbase = (i * 4 + w) * 64;
        int chunk = cbase + lane;
        int r = chunk >> 3, c8 = (chunk & 7) ^ (r & 7);
        gl_lds16(base + (size_t)(kt0 + r) * 2304 + 768 + h * 64 + c8 * 8, &Kl[cbase * 8]);
      }
      // stage Vt [64 d][128 tok] via DMA, swizzled
#pragma unroll
      for (int i = 0; i < 4; ++i) {
        int cbase = (i * 4 + w) * 64;
        int chunk = cbase + lane;
        int r = chunk >> 4, c16 = (chunk & 15) ^ (r & 7);
        gl_lds16(vbase + (size_t)r * 2048 + kt0 + c16 * 8, &Vl[cbase * 8]);
      }
      __syncthreads();

      // S = Q @ K^T : 16x128 per wave
      f32x4 S[8];
#pragma unroll
      for (int nt = 0; nt < 8; ++nt) {
        bf16x8 k0 = *(const bf16x8*)&Kl[(nt * 16 + l16) * 64 + (quad ^ swz) * 8];
        bf16x8 k1 = *(const bf16x8*)&Kl[(nt * 16 + l16) * 64 + ((4 + quad) ^ swz) * 8];
        f32x4 z = {};
        z = __builtin_amdgcn_mfma_f32_16x16x32_bf16(qf0, k0, z, 0, 0, 0);
        S[nt] = __builtin_amdgcn_mfma_f32_16x16x32_bf16(qf1, k1, z, 0, 0, 0);
      }

      // softmax, fixed max=0; mask only on the (peeled) diagonal block
      if (kb == nkb - 1) {
#pragma unroll
        for (int nt = 0; nt < 8; ++nt) {
          int tk = kt0 + nt * 16 + l16;
#pragma unroll
          for (int i = 0; i < 4; ++i) {
            float p = exp2f(S[nt][i] * sc);
            if (tk > qw + quad * 4 + i) p = 0.f;
            l_i[i] += p;
            Pw[(quad * 4 + i) * 136 + nt * 16 + l16] =
                (u16)(__builtin_bit_cast(unsigned int, p) >> 16);
          }
        }
      } else {
#pragma unroll
        for (int nt = 0; nt < 8; ++nt)
#pragma unroll
          for (int i = 0; i < 4; ++i) {
            float p = exp2f(S[nt][i] * sc);
            l_i[i] += p;
            Pw[(quad * 4 + i) * 136 + nt * 16 + l16] =
                (u16)(__builtin_bit_cast(unsigned int, p) >> 16);
          }
      }

      asm volatile("s_waitcnt lgkmcnt(0)" ::: "memory");  // wave-local P visible

      // O += P @ V
#pragma unroll
      for (int c = 0; c < 4; ++c) {
        bf16x8 pf = *(const bf16x8*)&Pw[l16 * 136 + c * 32 + quad * 8];
#pragma unroll
        for (int dt = 0; dt < 4; ++dt) {
          bf16x8 vf = *(const bf16x8*)&Vl[(dt * 16 + l16) * 128 + ((c * 4 + quad) ^ swz) * 8];
          O[dt] = __builtin_amdgcn_mfma_f32_16x16x32_bf16(pf, vf, O[dt], 0, 0, 0);
        }
      }
    }

    // epilogue: reduce l across the 16-lane groups (once), divide, store
#pragma unroll
    for (int i = 0; i < 4; ++i) {
#pragma unroll
      for (int o = 1; o < 16; o <<= 1) l_i[i] += __shfl_xor(l_i[i], o);
    }
#pragma unroll
    for (int dt = 0; dt < 4; ++dt) {
#pragma unroll
      for (int i = 0; i < 4; ++i) {
        int tq = qw + quad * 4 + i;
        float ov = O[dt][i] / l_i[i];
        y[(size_t)(b * 2048 + tq) * 768 + h * 64 + dt * 16 + l16] = f2bf(ov);
      }
    }
  }
}

// ---------------- launch ----------------
extern "C" void kernel_launch(void* const* d_in, const int* in_sizes, int n_in,
                              void* d_out, int out_size, void* d_ws, size_t ws_size,
                              hipStream_t stream) {
  const float* x      = (const float*)d_in[0];
  const float* ln1_g  = (const float*)d_in[1];
  const float* ln1_b  = (const float*)d_in[2];
  const float* W_qkv  = (const float*)d_in[3];
  const float* W_attn = (const float*)d_in[4];
  const float* ln2_g  = (const float*)d_in[5];
  const float* ln2_b  = (const float*)d_in[6];
  const float* W_fc   = (const float*)d_in[7];
  const float* W_mlp  = (const float*)d_in[8];
  float* out = (float*)d_out;

  const int M = 4096;  // B*T
  char* p = (char*)d_ws;
  auto alloc = [&](size_t bytes) {
    char* r = p;
    p += (bytes + 255) & ~(size_t)255;
    return r;
  };
  u16* wt_qkv  = (u16*)alloc((size_t)2304 * 768 * 2);
  u16* wt_attn = (u16*)alloc((size_t)768 * 768 * 2);
  u16* wt_fc   = (u16*)alloc((size_t)3072 * 768 * 2);
  u16* wt_mlp  = (u16*)alloc((size_t)768 * 3072 * 2);
  u16* xn1     = (u16*)alloc((size_t)M * 768 * 2);
  u16* qkvb    = (u16*)alloc((size_t)M * 2304 * 2);
  u16* yb      = (u16*)alloc((size_t)M * 768 * 2);
  float* x1    = (float*)alloc((size_t)M * 768 * 4);
  u16* xn2     = (u16*)alloc((size_t)M * 768 * 2);
  u16* hb      = (u16*)alloc((size_t)M * 3072 * 2);
  u16* vt      = (u16*)alloc((size_t)24 * 64 * 2048 * 2);
  unsigned int* ctr = (unsigned int*)alloc(256);

  transpose_w<<<dim3(2304 / 32, 768 / 32), 256, 0, stream>>>(W_qkv, wt_qkv, 768, 2304);
  transpose_w<<<dim3(768 / 32, 768 / 32), 256, 0, stream>>>(W_attn, wt_attn, 768, 768);
  transpose_w<<<dim3(3072 / 32, 768 / 32), 256, 0, stream>>>(W_fc, wt_fc, 768, 3072);
  transpose_w<<<dim3(768 / 32, 3072 / 32), 256, 0, stream>>>(W_mlp, wt_mlp, 3072, 768);

  ln_rows<<<M, 192, 0, stream>>>(x, ln1_g, ln1_b, xn1);
  // QKV = xn1 @ W_qkv  -> bf16  (TN=128, 576 blocks)
  gemm_bt<0, 128, 1><<<dim3(2304 / 128, M / 128), 256, 0, stream>>>(
      xn1, wt_qkv, M, 2304, 768, nullptr, qkvb);
  transpose_v<<<dim3(32, 24), 256, 0, stream>>>(qkvb, vt);
  zero_counter<<<1, 64, 0, stream>>>(ctr);
  flash_attn<<<768, 256, 0, stream>>>(qkvb, vt, yb, ctr);
  // x1 = x + y @ W_attn_proj : seed x1 = x, then split-K2 atomic partials (768 blocks)
  copy_f32<<<(M * 768 / 4 + 255) / 256, 256, 0, stream>>>(x, x1, M * 768 / 4);
  gemm_bt<3, 64, 2><<<dim3(768 / 64, M / 128, 2), 256, 0, stream>>>(
      yb, wt_attn, M, 768, 768, x1, nullptr);
  ln_rows<<<M, 192, 0, stream>>>(x1, ln2_g, ln2_b, xn2);
  // h = gelu(xn2 @ W_fc) -> bf16  (TN=128, 768 blocks)
  gemm_bt<2, 128, 1><<<dim3(3072 / 128, M / 128), 256, 0, stream>>>(
      xn2, wt_fc, M, 3072, 768, nullptr, hb);
  // out = x1 + h @ W_mlp_proj : seed out = x1, then split-K2 atomic partials
  copy_f32<<<(M * 768 / 4 + 255) / 256, 256, 0, stream>>>(x1, out, M * 768 / 4);
  gemm_bt<3, 64, 2><<<dim3(768 / 64, M / 128, 2), 256, 0, stream>>>(
      hb, wt_mlp, M, 768, 3072, out, nullptr);
}

// Round 9
// 273.470 us; speedup vs baseline: 1.1238x; 1.1238x over previous
//
#include <hip/hip_runtime.h>
#include <cstdint>
#include <cstddef>

typedef unsigned short u16;
typedef __attribute__((ext_vector_type(4))) float f32x4;
typedef __attribute__((ext_vector_type(8))) short bf16x8;

__device__ __forceinline__ u16 f2bf(float f) {
  unsigned int u = __builtin_bit_cast(unsigned int, f);
  u += 0x7fffu + ((u >> 16) & 1u);
  return (u16)(u >> 16);
}

// async global->LDS DMA, 16B per lane. LDS dest = uniform base + lane*16.
__device__ __forceinline__ void gl_lds16(const u16* g, u16* lds_base) {
  __builtin_amdgcn_global_load_lds(
      (const __attribute__((address_space(1))) unsigned int*)g,
      (__attribute__((address_space(3))) unsigned int*)lds_base, 16, 0, 0);
}

// ---------------- all-weight transpose + fp32->bf16 (one dispatch) ----------------
__global__ __launch_bounds__(256) void transpose_all(const float* __restrict__ s0,
                                                     const float* __restrict__ s1,
                                                     const float* __restrict__ s2,
                                                     const float* __restrict__ s3,
                                                     u16* __restrict__ d0,
                                                     u16* __restrict__ d1,
                                                     u16* __restrict__ d2,
                                                     u16* __restrict__ d3) {
  __shared__ float tile[32][33];
  int idx = blockIdx.x;
  const float* src; u16* dst; int K, N, t;
  if (idx < 1728)      { src = s0; dst = d0; K = 768;  N = 2304; t = idx; }
  else if (idx < 2304) { src = s1; dst = d1; K = 768;  N = 768;  t = idx - 1728; }
  else if (idx < 4608) { src = s2; dst = d2; K = 768;  N = 3072; t = idx - 2304; }
  else                 { src = s3; dst = d3; K = 3072; N = 768;  t = idx - 4608; }
  int nt_n = N >> 5;
  int n0 = (t % nt_n) * 32, k0 = (t / nt_n) * 32;
  int tx = threadIdx.x & 31, ty = threadIdx.x >> 5;  // 32 x 8
#pragma unroll
  for (int i = 0; i < 4; ++i)
    tile[ty + i * 8][tx] = src[(size_t)(k0 + ty + i * 8) * N + n0 + tx];
  __syncthreads();
#pragma unroll
  for (int i = 0; i < 4; ++i)
    dst[(size_t)(n0 + ty + i * 8) * K + k0 + tx] = f2bf(tile[tx][ty + i * 8]);
}

// ---------------- V transpose: qkvb [B*T][2304] -> vt [24][64][2048]; also zeroes ctr ----
__global__ __launch_bounds__(256) void transpose_v(const u16* __restrict__ qkvb,
                                                   u16* __restrict__ vt,
                                                   unsigned int* __restrict__ ctr) {
  __shared__ u16 tile[64 * 72];
  if (blockIdx.x == 0 && blockIdx.y == 0 && threadIdx.x == 0) *ctr = 0u;
  int t0 = blockIdx.x * 64;
  int bh = blockIdx.y;
  int b = bh / 12, h = bh % 12;
  int tid = threadIdx.x;
  int c8 = tid & 7, r = tid >> 3;
#pragma unroll
  for (int i = 0; i < 2; ++i) {
    int rr = r + i * 32;
    *(uint4*)&tile[rr * 72 + c8 * 8] =
        *(const uint4*)&qkvb[(size_t)(b * 2048 + t0 + rr) * 2304 + 1536 + h * 64 + c8 * 8];
  }
  __syncthreads();
#pragma unroll
  for (int i = 0; i < 2; ++i) {
    int dr = r + i * 32;
    u16 tmp[8];
#pragma unroll
    for (int j = 0; j < 8; ++j) tmp[j] = tile[(c8 * 8 + j) * 72 + dr];
    *(uint4*)&vt[((size_t)bh * 64 + dr) * 2048 + t0 + c8 * 8] = *(uint4*)tmp;
  }
}

// ---------------- LayerNorm (row = 768 fp32) -> bf16, float4 loads ----------------
__global__ __launch_bounds__(192) void ln_rows(const float* __restrict__ x,
                                               const float* __restrict__ g,
                                               const float* __restrict__ bb,
                                               u16* __restrict__ out) {
  int row = blockIdx.x;
  int t = threadIdx.x;  // 0..191, one float4 each
  float4 v = *(const float4*)(x + (size_t)row * 768 + t * 4);
  float s = v.x + v.y + v.z + v.w;
  float sq = v.x * v.x + v.y * v.y + v.z * v.z + v.w * v.w;
#pragma unroll
  for (int o = 32; o > 0; o >>= 1) {
    s += __shfl_down(s, o);
    sq += __shfl_down(sq, o);
  }
  __shared__ float ss[3], s2[3];
  int w = t >> 6;
  if ((t & 63) == 0) { ss[w] = s; s2[w] = sq; }
  __syncthreads();
  s = ss[0] + ss[1] + ss[2];
  sq = s2[0] + s2[1] + s2[2];
  float mu = s * (1.f / 768.f);
  float var = sq * (1.f / 768.f) - mu * mu;
  float rs = rsqrtf(var + 1e-5f);
  float4 gv = *(const float4*)(g + t * 4);
  float4 bv = *(const float4*)(bb + t * 4);
  u16 o4[4];
  o4[0] = f2bf((v.x - mu) * rs * gv.x + bv.x);
  o4[1] = f2bf((v.y - mu) * rs * gv.y + bv.y);
  o4[2] = f2bf((v.z - mu) * rs * gv.z + bv.z);
  o4[3] = f2bf((v.w - mu) * rs * gv.w + bv.w);
  *(uint2*)(out + (size_t)row * 768 + t * 4) = *(uint2*)o4;
}

// ---------------- bf16 MFMA GEMM: C = A[M,K] @ BT[N,K]^T ----------------
// Double-buffered single-barrier pipeline: per iter -> barrier; issue DMA(next tile);
// compute current tile (DMA flight hidden behind compute; drain at next barrier).
// Block tile TM x 64, 4 waves stacked on M. TM=128 (MT=2) or TM=64 (MT=1).
// EPI: 0 = store bf16; 1 = residual(fp32) add, store fp32; 2 = exact GELU -> bf16
template <int EPI, int TM>
__global__ __launch_bounds__(256, 3) void gemm_bt(const u16* __restrict__ A,
                                                  const u16* __restrict__ BT,
                                                  int M, int N, int K,
                                                  float* __restrict__ outF,
                                                  u16* __restrict__ outB,
                                                  const float* __restrict__ res) {
  constexpr int MT = TM / 64;  // 16-row m-frags per wave (TM/4 rows per wave)
  __shared__ __align__(16) u16 Al[2][TM * 64];
  __shared__ __align__(16) u16 Bl[2][64 * 64];
  int tid = threadIdx.x;
  int lane = tid & 63, w = tid >> 6;
  int l16 = lane & 15, quad = lane >> 4;
  int swz = l16 & 7;
  size_t rowA0 = (size_t)blockIdx.y * TM;
  size_t rowB0 = (size_t)blockIdx.x * 64;

  auto stage = [&](int buf, int k0) {
#pragma unroll
    for (int i = 0; i < TM / 32; ++i) {
      int cbase = (i * 4 + w) * 64;
      int chunk = cbase + lane;
      int r = chunk >> 3, c8 = (chunk & 7) ^ (r & 7);  // swizzled source chunk
      gl_lds16(&A[(rowA0 + r) * (size_t)K + k0 + c8 * 8], &Al[buf][cbase * 8]);
    }
#pragma unroll
    for (int i = 0; i < 2; ++i) {
      int cbase = (i * 4 + w) * 64;
      int chunk = cbase + lane;
      int r = chunk >> 3, c8 = (chunk & 7) ^ (r & 7);
      gl_lds16(&BT[(rowB0 + r) * (size_t)K + k0 + c8 * 8], &Bl[buf][cbase * 8]);
    }
  };

  f32x4 acc[MT][4] = {};
  stage(0, 0);
  int cur = 0;
  for (int k0 = 0; k0 < K; k0 += 64) {
    __syncthreads();  // drains DMA for buf[cur] (in flight during prev compute);
                      // rendezvous frees buf[cur^1] for overwrite
    if (k0 + 64 < K) stage(cur ^ 1, k0 + 64);
#pragma unroll
    for (int ks = 0; ks < 2; ++ks) {
      int c = ks * 4 + quad;
      bf16x8 af[MT], bf[4];
#pragma unroll
      for (int mt = 0; mt < MT; ++mt)
        af[mt] = *(const bf16x8*)&Al[cur][(w * (TM / 4) + mt * 16 + l16) * 64 + (c ^ swz) * 8];
#pragma unroll
      for (int nt = 0; nt < 4; ++nt)
        bf[nt] = *(const bf16x8*)&Bl[cur][(nt * 16 + l16) * 64 + (c ^ swz) * 8];
#pragma unroll
      for (int mt = 0; mt < MT; ++mt)
#pragma unroll
        for (int nt = 0; nt < 4; ++nt)
          acc[mt][nt] = __builtin_amdgcn_mfma_f32_16x16x32_bf16(af[mt], bf[nt], acc[mt][nt], 0, 0, 0);
    }
    cur ^= 1;
  }

#pragma unroll
  for (int mt = 0; mt < MT; ++mt) {
#pragma unroll
    for (int i = 0; i < 4; ++i) {
      size_t row = rowA0 + w * (TM / 4) + mt * 16 + quad * 4 + i;
#pragma unroll
      for (int nt = 0; nt < 4; ++nt) {
        size_t col = rowB0 + nt * 16 + l16;
        float v = acc[mt][nt][i];
        if (EPI == 0) {
          outB[row * N + col] = f2bf(v);
        } else if (EPI == 1) {
          outF[row * N + col] = res[row * N + col] + v;
        } else {
          float ge = 0.5f * v * (1.f + erff(v * 0.70710678118654752f));
          outB[row * N + col] = f2bf(ge);
        }
      }
    }
  }
}

// ---------------- causal flash attention (r7 version: LDS-staged, swizzled, KB=128) ----
__global__ __launch_bounds__(256, 3) void flash_attn(const u16* __restrict__ qkv,
                                                     const u16* __restrict__ vt,
                                                     u16* __restrict__ y,
                                                     unsigned int* __restrict__ ctr) {
  __shared__ __align__(16) u16 Kl[128 * 64];   // [tok][d], chunk-swizzled
  __shared__ __align__(16) u16 Vl[64 * 128];   // [d][tok], chunk-swizzled
  __shared__ __align__(16) u16 Pl[4][16 * 136];
  __shared__ unsigned int s_unit;

  int tid = threadIdx.x;
  int lane = tid & 63, w = tid >> 6;
  int l16 = lane & 15, quad = lane >> 4;
  int swz = l16 & 7;
  u16* Pw = &Pl[w][0];

  for (;;) {
    __syncthreads();
    if (tid == 0) s_unit = atomicAdd(ctr, 1u);
    __syncthreads();
    unsigned int u = s_unit;
    if (u >= 768u) return;

    int qt = 31 - (int)(u / 24u);  // heavy q-tiles first
    int bh = (int)(u % 24u);
    int b = bh / 12, h = bh % 12;
    int qw = qt * 64 + w * 16;

    const u16* base = qkv + (size_t)b * 2048 * 2304;
    const u16* vbase = vt + (size_t)bh * 64 * 2048;

    bf16x8 qf0, qf1;
    {
      const u16* qp = base + (size_t)(qw + l16) * 2304 + h * 64 + quad * 8;
      qf0 = *(const bf16x8*)qp;
      qf1 = *(const bf16x8*)(qp + 32);
    }

    f32x4 O[4] = {};
    float l_i[4] = {0.f, 0.f, 0.f, 0.f};  // per-lane partial row sums

    int nkb = qt / 2 + 1;
    const float sc = 0.125f * 1.44269504088896340736f;
    for (int kb = 0; kb < nkb; ++kb) {
      int kt0 = kb << 7;
      __syncthreads();
#pragma unroll
      for (int i = 0; i < 4; ++i) {
        int cbase = (i * 4 + w) * 64;
        int chunk = cbase + lane;
        int r = chunk >> 3, c8 = (chunk & 7) ^ (r & 7);
        gl_lds16(base + (size_t)(kt0 + r) * 2304 + 768 + h * 64 + c8 * 8, &Kl[cbase * 8]);
      }
#pragma unroll
      for (int i = 0; i < 4; ++i) {
        int cbase = (i * 4 + w) * 64;
        int chunk = cbase + lane;
        int r = chunk >> 4, c16 = (chunk & 15) ^ (r & 7);
        gl_lds16(vbase + (size_t)r * 2048 + kt0 + c16 * 8, &Vl[cbase * 8]);
      }
      __syncthreads();

      f32x4 S[8];
#pragma unroll
      for (int nt = 0; nt < 8; ++nt) {
        bf16x8 k0 = *(const bf16x8*)&Kl[(nt * 16 + l16) * 64 + (quad ^ swz) * 8];
        bf16x8 k1 = *(const bf16x8*)&Kl[(nt * 16 + l16) * 64 + ((4 + quad) ^ swz) * 8];
        f32x4 z = {};
        z = __builtin_amdgcn_mfma_f32_16x16x32_bf16(qf0, k0, z, 0, 0, 0);
        S[nt] = __builtin_amdgcn_mfma_f32_16x16x32_bf16(qf1, k1, z, 0, 0, 0);
      }

      bool diag = (kb == nkb - 1);
#pragma unroll
      for (int nt = 0; nt < 8; ++nt) {
        int tk = kt0 + nt * 16 + l16;
#pragma unroll
        for (int i = 0; i < 4; ++i) {
          float p = exp2f(S[nt][i] * sc);
          if (diag && tk > qw + quad * 4 + i) p = 0.f;
          l_i[i] += p;
          Pw[(quad * 4 + i) * 136 + nt * 16 + l16] =
              (u16)(__builtin_bit_cast(unsigned int, p) >> 16);
        }
      }

      asm volatile("s_waitcnt lgkmcnt(0)" ::: "memory");  // wave-local P visible

#pragma unroll
      for (int c = 0; c < 4; ++c) {
        bf16x8 pf = *(const bf16x8*)&Pw[l16 * 136 + c * 32 + quad * 8];
#pragma unroll
        for (int dt = 0; dt < 4; ++dt) {
          bf16x8 vf = *(const bf16x8*)&Vl[(dt * 16 + l16) * 128 + ((c * 4 + quad) ^ swz) * 8];
          O[dt] = __builtin_amdgcn_mfma_f32_16x16x32_bf16(pf, vf, O[dt], 0, 0, 0);
        }
      }
    }

#pragma unroll
    for (int i = 0; i < 4; ++i) {
#pragma unroll
      for (int o = 1; o < 16; o <<= 1) l_i[i] += __shfl_xor(l_i[i], o);
    }
#pragma unroll
    for (int dt = 0; dt < 4; ++dt) {
#pragma unroll
      for (int i = 0; i < 4; ++i) {
        int tq = qw + quad * 4 + i;
        float ov = O[dt][i] / l_i[i];
        y[(size_t)(b * 2048 + tq) * 768 + h * 64 + dt * 16 + l16] = f2bf(ov);
      }
    }
  }
}

// ---------------- launch ----------------
extern "C" void kernel_launch(void* const* d_in, const int* in_sizes, int n_in,
                              void* d_out, int out_size, void* d_ws, size_t ws_size,
                              hipStream_t stream) {
  const float* x      = (const float*)d_in[0];
  const float* ln1_g  = (const float*)d_in[1];
  const float* ln1_b  = (const float*)d_in[2];
  const float* W_qkv  = (const float*)d_in[3];
  const float* W_attn = (const float*)d_in[4];
  const float* ln2_g  = (const float*)d_in[5];
  const float* ln2_b  = (const float*)d_in[6];
  const float* W_fc   = (const float*)d_in[7];
  const float* W_mlp  = (const float*)d_in[8];
  float* out = (float*)d_out;

  const int M = 4096;  // B*T
  char* p = (char*)d_ws;
  auto alloc = [&](size_t bytes) {
    char* r = p;
    p += (bytes + 255) & ~(size_t)255;
    return r;
  };
  u16* wt_qkv  = (u16*)alloc((size_t)2304 * 768 * 2);
  u16* wt_attn = (u16*)alloc((size_t)768 * 768 * 2);
  u16* wt_fc   = (u16*)alloc((size_t)3072 * 768 * 2);
  u16* wt_mlp  = (u16*)alloc((size_t)768 * 3072 * 2);
  u16* xn1     = (u16*)alloc((size_t)M * 768 * 2);
  u16* qkvb    = (u16*)alloc((size_t)M * 2304 * 2);
  u16* yb      = (u16*)alloc((size_t)M * 768 * 2);
  float* x1    = (float*)alloc((size_t)M * 768 * 4);
  u16* xn2     = (u16*)alloc((size_t)M * 768 * 2);
  u16* hb      = (u16*)alloc((size_t)M * 3072 * 2);
  u16* vt      = (u16*)alloc((size_t)24 * 64 * 2048 * 2);
  unsigned int* ctr = (unsigned int*)alloc(256);

  // all 4 weight transposes in one dispatch (6912 tiles)
  transpose_all<<<6912, 256, 0, stream>>>(W_qkv, W_attn, W_fc, W_mlp,
                                          wt_qkv, wt_attn, wt_fc, wt_mlp);

  ln_rows<<<M, 192, 0, stream>>>(x, ln1_g, ln1_b, xn1);
  // QKV = xn1 @ W_qkv -> bf16  (TM=128: 18x32 = 576... now 36? N/64=36 x M/128=32 = 1152 blocks)
  gemm_bt<0, 128><<<dim3(2304 / 64, M / 128), 256, 0, stream>>>(xn1, wt_qkv, M, 2304, 768,
                                                                nullptr, qkvb, nullptr);
  transpose_v<<<dim3(32, 24), 256, 0, stream>>>(qkvb, vt, ctr);
  flash_attn<<<768, 256, 0, stream>>>(qkvb, vt, yb, ctr);
  // x1 = x + y @ W_attn_proj -> fp32  (TM=64: 12 x 64 = 768 blocks)
  gemm_bt<1, 64><<<dim3(768 / 64, M / 64), 256, 0, stream>>>(yb, wt_attn, M, 768, 768,
                                                             x1, nullptr, x);
  ln_rows<<<M, 192, 0, stream>>>(x1, ln2_g, ln2_b, xn2);
  // h = gelu(xn2 @ W_fc) -> bf16  (TM=128: 48 x 32 = 1536 blocks)
  gemm_bt<2, 128><<<dim3(3072 / 64, M / 128), 256, 0, stream>>>(xn2, wt_fc, M, 3072, 768,
                                                                nullptr, hb, nullptr);
  // out = x1 + h @ W_mlp_proj -> fp32  (TM=64: 768 blocks)
  gemm_bt<1, 64><<<dim3(768 / 64, M / 64), 256, 0, stream>>>(hb, wt_mlp, M, 768, 3072,
                                                             out, nullptr, x1);
}